// Round 8
// baseline (188.755 us; speedup 1.0000x reference)
//
#include <hip/hip_runtime.h>

#define S 2048
#define D 1024
#define NH 16
#define HD 64
#define N3 3072         // 3 * D
#define M 4096          // T * B

typedef short s16x8 __attribute__((ext_vector_type(8)));
typedef _Float16 f16x8 __attribute__((ext_vector_type(8)));
typedef float f32x4 __attribute__((ext_vector_type(4)));
typedef unsigned int u32;
typedef u32 u32x4 __attribute__((ext_vector_type(4)));

__device__ __forceinline__ unsigned short f2bf(float f) {
  unsigned u = __builtin_bit_cast(unsigned, f);
  u += 0x7fffu + ((u >> 16) & 1u);
  return (unsigned short)(u >> 16);
}
__device__ __forceinline__ float bf2f(unsigned short h) {
  return __builtin_bit_cast(float, (unsigned)h << 16);
}
__device__ __forceinline__ unsigned short f2h(float f) {
  _Float16 h = (_Float16)f;
  return __builtin_bit_cast(unsigned short, h);
}

__device__ __forceinline__ float wsum(float v) {
  #pragma unroll
  for (int m = 1; m < 64; m <<= 1) v += __shfl_xor(v, m, 64);
  return v;
}

__device__ __forceinline__ void gload_lds16(const unsigned short* g, unsigned short* l) {
  __builtin_amdgcn_global_load_lds(
      (const __attribute__((address_space(1))) u32*)g,
      (__attribute__((address_space(3))) u32*)l, 16, 0, 0);
}
__device__ __forceinline__ void gload_lds4(const float* g, float* l) {
  __builtin_amdgcn_global_load_lds(
      (const __attribute__((address_space(1))) u32*)g,
      (__attribute__((address_space(3))) u32*)l, 4, 0, 0);
}

// ---------------------------------------------------------------------------
// Kernel 0: split f32 -> 2x fp16 limbs (verified r4).
// ---------------------------------------------------------------------------
__global__ __launch_bounds__(256) void split_k(const float* __restrict__ q,
                                               const float* __restrict__ w,
                                               unsigned short* __restrict__ A1,
                                               unsigned short* __restrict__ A2,
                                               unsigned short* __restrict__ W1,
                                               unsigned short* __restrict__ W2) {
  const size_t gid = (size_t)blockIdx.x * 256 + threadIdx.x;   // quad index
  const size_t NA = (size_t)M * D / 4;                          // 1048576
  float4 x;
  unsigned short* p1; unsigned short* p2; size_t qi; float scale;
  if (gid < NA) {
    qi = gid;  x = ((const float4*)q)[qi];
    p1 = A1; p2 = A2; scale = 64.f;
  } else {
    qi = gid - NA;  x = ((const float4*)w)[qi];
    p1 = W1; p2 = W2; scale = 1024.f;
  }
  float e[4] = {x.x * scale, x.y * scale, x.z * scale, x.w * scale};
  unsigned short h1[4], h2[4];
  #pragma unroll
  for (int i = 0; i < 4; ++i) {
    _Float16 a = (_Float16)e[i];
    float r = e[i] - (float)a;
    _Float16 b = (_Float16)r;
    h1[i] = __builtin_bit_cast(unsigned short, a);
    h2[i] = __builtin_bit_cast(unsigned short, b);
  }
  *(ushort4*)&p1[qi * 4] = make_ushort4(h1[0], h1[1], h1[2], h1[3]);
  *(ushort4*)&p2[qi * 4] = make_ushort4(h2[0], h2[1], h2[2], h2[3]);
}

// ---------------------------------------------------------------------------
// Kernel 1: emulated-f32 GEMM on fp16 MFMA (verified r4, unchanged).
// ---------------------------------------------------------------------------
__global__ __launch_bounds__(256) void gemm_mfma(const unsigned short* __restrict__ A1,
                                                 const unsigned short* __restrict__ A2,
                                                 const unsigned short* __restrict__ W1,
                                                 const unsigned short* __restrict__ W2,
                                                 const float* __restrict__ bias,
                                                 float* __restrict__ C) {
  __shared__ unsigned short As[128 * 64];
  __shared__ unsigned short Bs[128 * 64];
  const int tid = threadIdx.x;
  const int w = tid >> 6, l = tid & 63;
  const int lo = l & 15, hi = l >> 4;
  const int n0 = blockIdx.x * 128, m0 = blockIdx.y * 128;
  const int wr = w >> 1, wc = w & 1;          // wave tile 64x64

  const int nseg = (n0 >= 2048) ? 1 : 3;

  const int srow = (tid >> 3) & 31;
  const int skc = tid & 7;

  f32x4 acc[4][4];
  #pragma unroll
  for (int mi = 0; mi < 4; ++mi)
    #pragma unroll
    for (int nj = 0; nj < 4; ++nj) acc[mi][nj] = (f32x4){0.f, 0.f, 0.f, 0.f};

  for (int s = 0; s < 3; ++s) {
    if (s >= nseg) break;
    const unsigned short* Ab;
    const unsigned short* Bb;
    switch (s) {                               // uniform scalar branch
      case 0: Ab = A1; Bb = W1; break;
      case 1: Ab = A2; Bb = W1; break;
      default: Ab = A1; Bb = W2; break;
    }
    Ab += (size_t)m0 * D;
    Bb += (size_t)n0 * D;

    for (int k0 = 0; k0 < D; k0 += 64) {
      __syncthreads();                         // prior iter's LDS reads done
      #pragma unroll
      for (int c = 0; c < 4; ++c) {
        const int row = c * 32 + srow;
        const int koct = skc ^ (row & 7);      // pre-swizzled source
        gload_lds16(Ab + (size_t)row * D + k0 + koct * 8,
                    As + c * 2048 + w * 512);
        gload_lds16(Bb + (size_t)row * D + k0 + koct * 8,
                    Bs + c * 2048 + w * 512);
      }
      __syncthreads();

      f16x8 af[4][2], bf[4][2];
      #pragma unroll
      for (int mi = 0; mi < 4; ++mi)
        #pragma unroll
        for (int ks = 0; ks < 2; ++ks) {
          const int row = wr * 64 + mi * 16 + lo;
          const int koct = (ks * 4 + hi) ^ (lo & 7);
          af[mi][ks] = *(const f16x8*)&As[row * 64 + koct * 8];
        }
      #pragma unroll
      for (int nj = 0; nj < 4; ++nj)
        #pragma unroll
        for (int ks = 0; ks < 2; ++ks) {
          const int row = wc * 64 + nj * 16 + lo;
          const int koct = (ks * 4 + hi) ^ (lo & 7);
          bf[nj][ks] = *(const f16x8*)&Bs[row * 64 + koct * 8];
        }
      #pragma unroll
      for (int mi = 0; mi < 4; ++mi)
        #pragma unroll
        for (int nj = 0; nj < 4; ++nj)
          #pragma unroll
          for (int ks = 0; ks < 2; ++ks)
            acc[mi][nj] = __builtin_amdgcn_mfma_f32_16x16x32_f16(
                af[mi][ks], bf[nj][ks], acc[mi][nj], 0, 0, 0);
    }
  }

  #pragma unroll
  for (int mi = 0; mi < 4; ++mi)
    #pragma unroll
    for (int nj = 0; nj < 4; ++nj) {
      const int n = n0 + wc * 64 + nj * 16 + lo;
      const float bj = bias[n];
      #pragma unroll
      for (int r = 0; r < 4; ++r) {
        const int m = m0 + wr * 64 + mi * 16 + hi * 4 + r;
        C[(size_t)m * N3 + n] = acc[mi][nj][r] * (1.f / 65536.f) + bj;
      }
    }
}

// ---------------------------------------------------------------------------
// Kernel 2: per-row stats + layout conversion.
// r8: UNFOLDED limbs restored (the r2-r5 config, measured absmax 9.77e-4):
// qc/kc centered bf16 2-limb + separate rs = d>0 ? rsqrt(d) : 0.
// V stored fp16.
// ---------------------------------------------------------------------------
__global__ __launch_bounds__(256) void stats_k(const float* __restrict__ qkv,
                                               unsigned short* __restrict__ qhi,
                                               unsigned short* __restrict__ qlo,
                                               unsigned short* __restrict__ khi,
                                               unsigned short* __restrict__ klo,
                                               unsigned short* __restrict__ vt,
                                               float* __restrict__ rs) {
  __shared__ unsigned short VsT[64][65];
  const int tt = blockIdx.x, bh = blockIdx.y;
  const int b = bh >> 4, h = bh & 15;
  const int w = threadIdx.x >> 6, l = threadIdx.x & 63;

  for (int rr = 0; rr < 16; ++rr) {
    const int t = tt * 64 + w * 16 + rr;
    const size_t base = (size_t)(t * 2 + b) * N3 + h * HD;
    const float q = qkv[base + l];
    const float k = qkv[base + D + l];
    const float v = qkv[base + 2 * D + l];
    const float qm = wsum(q) * (1.f / 64.f);
    const float km = wsum(k) * (1.f / 64.f);
    const float qcv = q - qm, kcv = k - km;
    const float d = wsum(qcv * kcv);
    float rv = 0.f;
    if (d > 0.f) {
      rv = rsqrtf(d);
      rv = rv * (1.5f - 0.5f * d * rv * rv);   // one NR step
    }
    const size_t ro = ((size_t)bh * S + t) * HD + l;
    const unsigned short qh = f2bf(qcv);
    const unsigned short kh = f2bf(kcv);
    qhi[ro] = qh;  qlo[ro] = f2bf(qcv - bf2f(qh));
    khi[ro] = kh;  klo[ro] = f2bf(kcv - bf2f(kh));
    if (l == 0) rs[(size_t)bh * S + t] = rv;
    VsT[l][w * 16 + rr] = f2h(v);              // fp16 V
  }
  __syncthreads();
  const int dd = threadIdx.x >> 2, seg = threadIdx.x & 3;
  unsigned pk[8];
  #pragma unroll
  for (int e = 0; e < 8; ++e) {
    unsigned l2 = VsT[dd][seg * 16 + 2 * e];
    unsigned h2 = VsT[dd][seg * 16 + 2 * e + 1];
    pk[e] = l2 | (h2 << 16);
  }
  unsigned short* dst = vt + ((size_t)bh * HD + dd) * S + tt * 64 + seg * 16;
  *(uint4*)dst       = make_uint4(pk[0], pk[1], pk[2], pk[3]);
  *(uint4*)(dst + 8) = make_uint4(pk[4], pk[5], pk[6], pk[7]);
}

// ---------------------------------------------------------------------------
// Kernel 3: fused correlation-softmax-PV, swapped QK^T, KV-SPLIT-2.
// Each block handles half the KV range (j in [half*1024, half*1024+1024)),
// writing UNNORMALIZED O-partials (f32) + den-partials; combine_k finishes.
// 8192 waves -> 32 waves/CU (was 16): drains absorbed by other blocks.
// rsq_i is lane-local (q=lo); rj staged as a 256B LDS tile (broadcast reads).
// T5 setprio around the compute phase (independent blocks -> role split).
// ---------------------------------------------------------------------------
__global__ __launch_bounds__(512) void attn_k(const unsigned short* __restrict__ qhi,
                                              const unsigned short* __restrict__ qlo,
                                              const unsigned short* __restrict__ khi,
                                              const unsigned short* __restrict__ klo,
                                              const unsigned short* __restrict__ vt,
                                              const float* __restrict__ rs,
                                              float* __restrict__ O0,
                                              float* __restrict__ O1,
                                              float* __restrict__ D0,
                                              float* __restrict__ D1) {
  __shared__ unsigned short Kh[64 * 64];   // [row j][64 d], XOR-granule
  __shared__ unsigned short Kl[64 * 64];
  __shared__ unsigned short Vsm[64 * 64];  // [row d][64 j], XOR-granule
  __shared__ float Rsl[64];

  const int tid = threadIdx.x;
  const int w = tid >> 6, l = tid & 63;
  const int lo = l & 15, hi = l >> 4;

  // T1: XCD swizzle, 1024 = 8 x 128 exact -> bijective; 4 bh per XCD.
  const int wgid = blockIdx.x;
  const int orig = (wgid & 7) * 128 + (wgid >> 3);
  const int bh = orig >> 5, qt = (orig >> 1) & 15, half = orig & 1;

  const unsigned short* qhb = qhi + (size_t)bh * S * HD;
  const unsigned short* qlb = qlo + (size_t)bh * S * HD;
  const unsigned short* khb = khi + (size_t)bh * S * HD;
  const unsigned short* klb = klo + (size_t)bh * S * HD;
  const unsigned short* vbase = vt + (size_t)bh * HD * S;
  const float* rbase = rs + (size_t)bh * S;
  const int qrow0 = qt * 128 + w * 16;     // wave owns 16 q-rows

  // staging map: thread stages one 16B chunk per plane; linear LDS dest
  const int srow = tid >> 3;               // 0..63
  const int sg = (tid & 7) ^ (srow & 7);   // pre-swizzled source granule

  // Q fragments (B-operand): lane holds q-row qrow0+lo, d-chunk ks*32+hi*8
  s16x8 aqh[2], aql[2];
  #pragma unroll
  for (int ks = 0; ks < 2; ++ks) {
    const size_t off = (size_t)(qrow0 + lo) * HD + ks * 32 + hi * 8;
    aqh[ks] = *(const s16x8*)(qhb + off);
    aql[ks] = *(const s16x8*)(qlb + off);
  }
  const float rsq = rbase[qrow0 + lo];     // lane-local row scale (q = lo)

  f32x4 oacc[4];
  float den = 0.f;
  #pragma unroll
  for (int nd = 0; nd < 4; ++nd) oacc[nd] = (f32x4){0.f, 0.f, 0.f, 0.f};

  const int sel = hi >> 1;
  const int srcA = lo + ((hi & 1) << 5);
  const int srcB = srcA + 16;

  const int jbeg = half * 1024;
  for (int j0 = jbeg; j0 < jbeg + 1024; j0 += 64) {
    __syncthreads();                       // prior iter's LDS reads done
    {
      const size_t kgo = (size_t)(j0 + srow) * HD + sg * 8;
      gload_lds16(khb + kgo, Kh + w * 512);
      gload_lds16(klb + kgo, Kl + w * 512);
      gload_lds16(vbase + (size_t)srow * S + j0 + sg * 8, Vsm + w * 512);
      if (w == 0) gload_lds4(rbase + j0 + l, Rsl);
    }
    __syncthreads();                       // vmcnt(0) drain + barrier

    __builtin_amdgcn_s_setprio(1);
    // swapped QK^T: acc_s[nj] = S[q=lo][k=nj*16+hi*4+r], 3-product split
    u32 pk2[4][2];
    #pragma unroll
    for (int nj = 0; nj < 4; ++nj) {
      f32x4 acc = (f32x4){0.f, 0.f, 0.f, 0.f};
      #pragma unroll
      for (int ks = 0; ks < 2; ++ks) {
        const int off = (nj * 16 + lo) * 64 + (((ks * 4 + hi) ^ (lo & 7)) << 3);
        s16x8 akh = *(const s16x8*)&Kh[off];
        s16x8 akl = *(const s16x8*)&Kl[off];
        acc = __builtin_amdgcn_mfma_f32_16x16x32_bf16(akh, aqh[ks], acc, 0, 0, 0);
        acc = __builtin_amdgcn_mfma_f32_16x16x32_bf16(akl, aqh[ks], acc, 0, 0, 0);
        acc = __builtin_amdgcn_mfma_f32_16x16x32_bf16(akh, aql[ks], acc, 0, 0, 0);
      }
      float e[4];
      #pragma unroll
      for (int r = 0; r < 4; ++r) {
        const float rj = Rsl[nj * 16 + hi * 4 + r];        // broadcast read
        float c = fminf(1.f, fmaxf(-1.f, acc[r] * rsq * rj));
        e[r] = __expf(c);
        den += e[r];
      }
      pk2[nj][0] = __builtin_bit_cast(u32, __builtin_amdgcn_cvt_pkrtz(e[0], e[1]));
      pk2[nj][1] = __builtin_bit_cast(u32, __builtin_amdgcn_cvt_pkrtz(e[2], e[3]));
    }

    // in-register P transpose: pa[ks] = P[q=lo][k=ks*32+hi*8 .. +7]
    f16x8 pa[2];
    #pragma unroll
    for (int ks = 0; ks < 2; ++ks) {
      u32 a0 = __shfl(pk2[2 * ks][0], srcA, 64);
      u32 b0 = __shfl(pk2[2 * ks + 1][0], srcA, 64);
      u32 a1 = __shfl(pk2[2 * ks][1], srcA, 64);
      u32 b1 = __shfl(pk2[2 * ks + 1][1], srcA, 64);
      u32 a2 = __shfl(pk2[2 * ks][0], srcB, 64);
      u32 b2 = __shfl(pk2[2 * ks + 1][0], srcB, 64);
      u32 a3 = __shfl(pk2[2 * ks][1], srcB, 64);
      u32 b3 = __shfl(pk2[2 * ks + 1][1], srcB, 64);
      u32x4 u;
      u[0] = sel ? b0 : a0;
      u[1] = sel ? b1 : a1;
      u[2] = sel ? b2 : a2;
      u[3] = sel ? b3 : a3;
      pa[ks] = __builtin_bit_cast(f16x8, u);
    }

    // PV: O[q][d] += P V
    #pragma unroll
    for (int nd = 0; nd < 4; ++nd) {
      const int vrow = nd * 16 + lo;
      f16x8 bv0 = *(const f16x8*)&Vsm[vrow * 64 + ((hi ^ (lo & 7)) << 3)];
      f16x8 bv1 = *(const f16x8*)&Vsm[vrow * 64 + (((4 + hi) ^ (lo & 7)) << 3)];
      oacc[nd] = __builtin_amdgcn_mfma_f32_16x16x32_f16(pa[0], bv0, oacc[nd], 0, 0, 0);
      oacc[nd] = __builtin_amdgcn_mfma_f32_16x16x32_f16(pa[1], bv1, oacc[nd], 0, 0, 0);
    }
    __builtin_amdgcn_s_setprio(0);
  }

  float* Oh = half ? O1 : O0;
  float* Dh = half ? D1 : D0;

  // den: sum the 4 hi-partials for q = lo; store partial (no normalize)
  float d1 = den + __shfl_xor(den, 16, 64);
  float dtot = d1 + __shfl_xor(d1, 32, 64);
  if (hi == 0) Dh[(size_t)bh * S + qrow0 + lo] = dtot;

  #pragma unroll
  for (int nd = 0; nd < 4; ++nd)
    #pragma unroll
    for (int r = 0; r < 4; ++r) {
      const size_t row = (size_t)bh * S + qrow0 + hi * 4 + r;
      Oh[row * HD + nd * 16 + lo] = oacc[nd][r];
    }
}

// ---------------------------------------------------------------------------
// Kernel 4: combine halves: out = (O0+O1) / (D0+D1).
// ---------------------------------------------------------------------------
__global__ __launch_bounds__(256) void combine_k(const float* __restrict__ O0,
                                                 const float* __restrict__ O1,
                                                 const float* __restrict__ D0,
                                                 const float* __restrict__ D1,
                                                 float* __restrict__ out) {
  const size_t i4 = (size_t)blockIdx.x * 256 + threadIdx.x;  // float4 index
  const size_t row = i4 >> 4;                                // 16 float4/row
  float4 a = ((const float4*)O0)[i4];
  float4 b = ((const float4*)O1)[i4];
  const float inv = 1.f / (D0[row] + D1[row]);
  float4 o;
  o.x = (a.x + b.x) * inv;  o.y = (a.y + b.y) * inv;
  o.z = (a.z + b.z) * inv;  o.w = (a.w + b.w) * inv;
  ((float4*)out)[i4] = o;
}

extern "C" void kernel_launch(void* const* d_in, const int* in_sizes, int n_in,
                              void* d_out, int out_size, void* d_ws, size_t ws_size,
                              hipStream_t stream) {
  const float* query = (const float*)d_in[0];
  const float* W     = (const float*)d_in[1];
  const float* bias  = (const float*)d_in[2];
  float* out = (float*)d_out;
  char* ws = (char*)d_ws;

  float*          qkv = (float*)ws;                          // [0, 50331648) dead after stats_k
  // attn partials reuse the dead qkv region:
  float* O0 = (float*)ws;                                    // 16777216 B
  float* O1 = (float*)(ws + 16777216);                       // 16777216 B
  float* Dp0 = (float*)(ws + 33554432);                      //   262144 B
  float* Dp1 = (float*)(ws + 33816576);                      //   262144 B -> 34078720
  // fp16 split planes live only between split_k and gemm_mfma:
  unsigned short* A1 = (unsigned short*)(ws + 50331648);
  unsigned short* A2 = (unsigned short*)(ws + 58720256);
  unsigned short* W1 = (unsigned short*)(ws + 67108864);
  unsigned short* W2 = (unsigned short*)(ws + 73400320);
  // stats outputs reuse the (dead) split region:
  unsigned short* qhi = (unsigned short*)(ws + 50331648);
  unsigned short* qlo = (unsigned short*)(ws + 58720256);
  unsigned short* khi = (unsigned short*)(ws + 67108864);
  unsigned short* klo = (unsigned short*)(ws + 75497472);
  unsigned short* vt  = (unsigned short*)(ws + 83886080);
  float*          rsb = (float*)(ws + 92274688);

  split_k  <<<dim3(7168), 256, 0, stream>>>(query, W, A1, A2, W1, W2);
  gemm_mfma<<<dim3(24, 32), 256, 0, stream>>>(A1, A2, W1, W2, bias, qkv);
  stats_k  <<<dim3(32, 32), 256, 0, stream>>>(qkv, qhi, qlo, khi, klo, vt, rsb);
  attn_k   <<<dim3(1024), 512, 0, stream>>>(qhi, qlo, khi, klo, vt, rsb, O0, O1, Dp0, Dp1);
  combine_k<<<dim3(4096), 256, 0, stream>>>(O0, O1, Dp0, Dp1, out);
}

// Round 9
// 184.496 us; speedup vs baseline: 1.0231x; 1.0231x over previous
//
#include <hip/hip_runtime.h>

#define S 2048
#define D 1024
#define NH 16
#define HD 64
#define N3 3072         // 3 * D
#define M 4096          // T * B

typedef short s16x8 __attribute__((ext_vector_type(8)));
typedef _Float16 f16x8 __attribute__((ext_vector_type(8)));
typedef float f32x4 __attribute__((ext_vector_type(4)));
typedef float f32x16 __attribute__((ext_vector_type(16)));
typedef unsigned int u32;
typedef u32 u32x4 __attribute__((ext_vector_type(4)));

__device__ __forceinline__ unsigned short f2bf(float f) {
  unsigned u = __builtin_bit_cast(unsigned, f);
  u += 0x7fffu + ((u >> 16) & 1u);
  return (unsigned short)(u >> 16);
}
__device__ __forceinline__ float bf2f(unsigned short h) {
  return __builtin_bit_cast(float, (unsigned)h << 16);
}
__device__ __forceinline__ unsigned short f2h(float f) {
  _Float16 h = (_Float16)f;
  return __builtin_bit_cast(unsigned short, h);
}

__device__ __forceinline__ float wsum(float v) {
  #pragma unroll
  for (int m = 1; m < 64; m <<= 1) v += __shfl_xor(v, m, 64);
  return v;
}

__device__ __forceinline__ void gload_lds16(const unsigned short* g, unsigned short* l) {
  __builtin_amdgcn_global_load_lds(
      (const __attribute__((address_space(1))) u32*)g,
      (__attribute__((address_space(3))) u32*)l, 16, 0, 0);
}
__device__ __forceinline__ void gload_lds4(const float* g, float* l) {
  __builtin_amdgcn_global_load_lds(
      (const __attribute__((address_space(1))) u32*)g,
      (__attribute__((address_space(3))) u32*)l, 4, 0, 0);
}

// ---------------------------------------------------------------------------
// Kernel 0: split f32 -> 2x fp16 limbs (verified r4).
// ---------------------------------------------------------------------------
__global__ __launch_bounds__(256) void split_k(const float* __restrict__ q,
                                               const float* __restrict__ w,
                                               unsigned short* __restrict__ A1,
                                               unsigned short* __restrict__ A2,
                                               unsigned short* __restrict__ W1,
                                               unsigned short* __restrict__ W2) {
  const size_t gid = (size_t)blockIdx.x * 256 + threadIdx.x;   // quad index
  const size_t NA = (size_t)M * D / 4;                          // 1048576
  float4 x;
  unsigned short* p1; unsigned short* p2; size_t qi; float scale;
  if (gid < NA) {
    qi = gid;  x = ((const float4*)q)[qi];
    p1 = A1; p2 = A2; scale = 64.f;
  } else {
    qi = gid - NA;  x = ((const float4*)w)[qi];
    p1 = W1; p2 = W2; scale = 1024.f;
  }
  float e[4] = {x.x * scale, x.y * scale, x.z * scale, x.w * scale};
  unsigned short h1[4], h2[4];
  #pragma unroll
  for (int i = 0; i < 4; ++i) {
    _Float16 a = (_Float16)e[i];
    float r = e[i] - (float)a;
    _Float16 b = (_Float16)r;
    h1[i] = __builtin_bit_cast(unsigned short, a);
    h2[i] = __builtin_bit_cast(unsigned short, b);
  }
  *(ushort4*)&p1[qi * 4] = make_ushort4(h1[0], h1[1], h1[2], h1[3]);
  *(ushort4*)&p2[qi * 4] = make_ushort4(h2[0], h2[1], h2[2], h2[3]);
}

// ---------------------------------------------------------------------------
// Kernel 1: emulated-f32 GEMM on fp16 MFMA (verified r4, unchanged).
// ---------------------------------------------------------------------------
__global__ __launch_bounds__(256) void gemm_mfma(const unsigned short* __restrict__ A1,
                                                 const unsigned short* __restrict__ A2,
                                                 const unsigned short* __restrict__ W1,
                                                 const unsigned short* __restrict__ W2,
                                                 const float* __restrict__ bias,
                                                 float* __restrict__ C) {
  __shared__ unsigned short As[128 * 64];
  __shared__ unsigned short Bs[128 * 64];
  const int tid = threadIdx.x;
  const int w = tid >> 6, l = tid & 63;
  const int lo = l & 15, hi = l >> 4;
  const int n0 = blockIdx.x * 128, m0 = blockIdx.y * 128;
  const int wr = w >> 1, wc = w & 1;          // wave tile 64x64

  const int nseg = (n0 >= 2048) ? 1 : 3;

  const int srow = (tid >> 3) & 31;
  const int skc = tid & 7;

  f32x4 acc[4][4];
  #pragma unroll
  for (int mi = 0; mi < 4; ++mi)
    #pragma unroll
    for (int nj = 0; nj < 4; ++nj) acc[mi][nj] = (f32x4){0.f, 0.f, 0.f, 0.f};

  for (int s = 0; s < 3; ++s) {
    if (s >= nseg) break;
    const unsigned short* Ab;
    const unsigned short* Bb;
    switch (s) {                               // uniform scalar branch
      case 0: Ab = A1; Bb = W1; break;
      case 1: Ab = A2; Bb = W1; break;
      default: Ab = A1; Bb = W2; break;
    }
    Ab += (size_t)m0 * D;
    Bb += (size_t)n0 * D;

    for (int k0 = 0; k0 < D; k0 += 64) {
      __syncthreads();                         // prior iter's LDS reads done
      #pragma unroll
      for (int c = 0; c < 4; ++c) {
        const int row = c * 32 + srow;
        const int koct = skc ^ (row & 7);      // pre-swizzled source
        gload_lds16(Ab + (size_t)row * D + k0 + koct * 8,
                    As + c * 2048 + w * 512);
        gload_lds16(Bb + (size_t)row * D + k0 + koct * 8,
                    Bs + c * 2048 + w * 512);
      }
      __syncthreads();

      f16x8 af[4][2], bf[4][2];
      #pragma unroll
      for (int mi = 0; mi < 4; ++mi)
        #pragma unroll
        for (int ks = 0; ks < 2; ++ks) {
          const int row = wr * 64 + mi * 16 + lo;
          const int koct = (ks * 4 + hi) ^ (lo & 7);
          af[mi][ks] = *(const f16x8*)&As[row * 64 + koct * 8];
        }
      #pragma unroll
      for (int nj = 0; nj < 4; ++nj)
        #pragma unroll
        for (int ks = 0; ks < 2; ++ks) {
          const int row = wc * 64 + nj * 16 + lo;
          const int koct = (ks * 4 + hi) ^ (lo & 7);
          bf[nj][ks] = *(const f16x8*)&Bs[row * 64 + koct * 8];
        }
      #pragma unroll
      for (int mi = 0; mi < 4; ++mi)
        #pragma unroll
        for (int nj = 0; nj < 4; ++nj)
          #pragma unroll
          for (int ks = 0; ks < 2; ++ks)
            acc[mi][nj] = __builtin_amdgcn_mfma_f32_16x16x32_f16(
                af[mi][ks], bf[nj][ks], acc[mi][nj], 0, 0, 0);
    }
  }

  #pragma unroll
  for (int mi = 0; mi < 4; ++mi)
    #pragma unroll
    for (int nj = 0; nj < 4; ++nj) {
      const int n = n0 + wc * 64 + nj * 16 + lo;
      const float bj = bias[n];
      #pragma unroll
      for (int r = 0; r < 4; ++r) {
        const int m = m0 + wr * 64 + mi * 16 + hi * 4 + r;
        C[(size_t)m * N3 + n] = acc[mi][nj][r] * (1.f / 65536.f) + bj;
      }
    }
}

// ---------------------------------------------------------------------------
// Kernel 2: per-row stats + layout conversion (r8 config, verified 9.77e-4).
// ---------------------------------------------------------------------------
__global__ __launch_bounds__(256) void stats_k(const float* __restrict__ qkv,
                                               unsigned short* __restrict__ qhi,
                                               unsigned short* __restrict__ qlo,
                                               unsigned short* __restrict__ khi,
                                               unsigned short* __restrict__ klo,
                                               unsigned short* __restrict__ vt,
                                               float* __restrict__ rs) {
  __shared__ unsigned short VsT[64][65];
  const int tt = blockIdx.x, bh = blockIdx.y;
  const int b = bh >> 4, h = bh & 15;
  const int w = threadIdx.x >> 6, l = threadIdx.x & 63;

  for (int rr = 0; rr < 16; ++rr) {
    const int t = tt * 64 + w * 16 + rr;
    const size_t base = (size_t)(t * 2 + b) * N3 + h * HD;
    const float q = qkv[base + l];
    const float k = qkv[base + D + l];
    const float v = qkv[base + 2 * D + l];
    const float qm = wsum(q) * (1.f / 64.f);
    const float km = wsum(k) * (1.f / 64.f);
    const float qcv = q - qm, kcv = k - km;
    const float d = wsum(qcv * kcv);
    float rv = 0.f;
    if (d > 0.f) {
      rv = rsqrtf(d);
      rv = rv * (1.5f - 0.5f * d * rv * rv);   // one NR step
    }
    const size_t ro = ((size_t)bh * S + t) * HD + l;
    const unsigned short qh = f2bf(qcv);
    const unsigned short kh = f2bf(kcv);
    qhi[ro] = qh;  qlo[ro] = f2bf(qcv - bf2f(qh));
    khi[ro] = kh;  klo[ro] = f2bf(kcv - bf2f(kh));
    if (l == 0) rs[(size_t)bh * S + t] = rv;
    VsT[l][w * 16 + rr] = f2h(v);              // fp16 V
  }
  __syncthreads();
  const int dd = threadIdx.x >> 2, seg = threadIdx.x & 3;
  unsigned pk[8];
  #pragma unroll
  for (int e = 0; e < 8; ++e) {
    unsigned l2 = VsT[dd][seg * 16 + 2 * e];
    unsigned h2 = VsT[dd][seg * 16 + 2 * e + 1];
    pk[e] = l2 | (h2 << 16);
  }
  unsigned short* dst = vt + ((size_t)bh * HD + dd) * S + tt * 64 + seg * 16;
  *(uint4*)dst       = make_uint4(pk[0], pk[1], pk[2], pk[3]);
  *(uint4*)(dst + 8) = make_uint4(pk[4], pk[5], pk[6], pk[7]);
}

// ---------------------------------------------------------------------------
// Kernel 3: fused correlation-softmax-PV, swapped QK^T on 32x32x16 MFMA.
// r9: wave covers 32 q-rows with the SAME 24 ds_read_b128/iter as the old
// 16-row wave -> per-CU LDS-pipe cycles halve (the r5-r8 measured bound).
// C-layout (guide-verified): col=lane&31, row=(r&3)+8*(r>>2)+4*(lane>>5).
// P assembled in-register: 8 cvt_pkrtz + 8 shfl_xor(32)+cndmask per iter.
// No split, no combine: 512 blocks x 4 waves = exactly 2 blocks/CU.
// Numerics identical to r8 (bf16 3-product QK, fp16 P/V, unfolded rs).
// ---------------------------------------------------------------------------
__global__ __launch_bounds__(256) void attn_k(const unsigned short* __restrict__ qhi,
                                              const unsigned short* __restrict__ qlo,
                                              const unsigned short* __restrict__ khi,
                                              const unsigned short* __restrict__ klo,
                                              const unsigned short* __restrict__ vt,
                                              const float* __restrict__ rs,
                                              float* __restrict__ out) {
  __shared__ unsigned short Kh[64 * 64];   // [row j][64 d], XOR-granule
  __shared__ unsigned short Kl[64 * 64];
  __shared__ unsigned short Vsm[64 * 64];  // [row d][64 j], XOR-granule
  __shared__ float Rsl[64];

  const int tid = threadIdx.x;
  const int w = tid >> 6, l = tid & 63;
  const int lq = l & 31;                   // col q / A-row index
  const int h = l >> 5;                    // k-half selector
  const int l7 = l & 7;

  // T1: XCD-aware swizzle (512 = 8 XCD x 64, exact -> bijective).
  const int wgid = blockIdx.x;
  const int orig = (wgid & 7) * 64 + (wgid >> 3);
  const int bh = orig >> 4, qt = orig & 15;

  const unsigned short* qhb = qhi + (size_t)bh * S * HD;
  const unsigned short* qlb = qlo + (size_t)bh * S * HD;
  const unsigned short* khb = khi + (size_t)bh * S * HD;
  const unsigned short* klb = klo + (size_t)bh * S * HD;
  const unsigned short* vbase = vt + (size_t)bh * HD * S;
  const float* rbase = rs + (size_t)bh * S;
  const int qrow0 = qt * 128 + w * 32;     // wave owns 32 q-rows

  // staging map: 2 chunks of 32 rows; linear LDS dest, pre-swizzled source
  const int srow3 = l >> 3;                // 0..7 (row within wave's 8)
  const int sg = l7 ^ srow3;               // source granule

  // Q fragments (B-operand): lane holds q-row qrow0+lq, d-chunk kc*16+h*8
  s16x8 qfh[4], qfl[4];
  #pragma unroll
  for (int kc = 0; kc < 4; ++kc) {
    const size_t off = (size_t)(qrow0 + lq) * HD + kc * 16 + h * 8;
    qfh[kc] = *(const s16x8*)(qhb + off);
    qfl[kc] = *(const s16x8*)(qlb + off);
  }
  const float rsq = rbase[qrow0 + lq];     // lane-local row scale (q = lq)

  f32x16 oacc[2];
  oacc[0] = (f32x16)(0.f);
  oacc[1] = (f32x16)(0.f);
  float den = 0.f;

  for (int j0 = 0; j0 < S; j0 += 64) {
    __syncthreads();                       // prior iter's LDS reads done
    #pragma unroll
    for (int c = 0; c < 2; ++c) {
      const int row = c * 32 + w * 8 + srow3;
      const int dst = c * 2048 + w * 512;  // wave-uniform LDS base (shorts)
      gload_lds16(khb + (size_t)(j0 + row) * HD + sg * 8, Kh + dst);
      gload_lds16(klb + (size_t)(j0 + row) * HD + sg * 8, Kl + dst);
      gload_lds16(vbase + (size_t)row * S + j0 + sg * 8, Vsm + dst);
    }
    if (w == 0) gload_lds4(rbase + j0 + l, Rsl);
    __syncthreads();                       // vmcnt(0) drain + barrier

    #pragma unroll
    for (int jblk = 0; jblk < 2; ++jblk) {
      // swapped QK^T: sacc[r] = S[j = jblk*32+(r&3)+8*(r>>2)+4h][q = lq]
      f32x16 sacc = (f32x16)(0.f);
      #pragma unroll
      for (int kc = 0; kc < 4; ++kc) {
        const int off = (jblk * 32 + lq) * 64 + (((kc * 2 + h) ^ l7) << 3);
        s16x8 akh = *(const s16x8*)&Kh[off];
        s16x8 akl = *(const s16x8*)&Kl[off];
        sacc = __builtin_amdgcn_mfma_f32_32x32x16_bf16(akh, qfh[kc], sacc, 0, 0, 0);
        sacc = __builtin_amdgcn_mfma_f32_32x32x16_bf16(akl, qfh[kc], sacc, 0, 0, 0);
        sacc = __builtin_amdgcn_mfma_f32_32x32x16_bf16(akh, qfl[kc], sacc, 0, 0, 0);
      }

      // softmax elements + fp16 packs (pk[g] covers regs 4g..4g+3)
      u32 pkA[4], pkB[4];
      #pragma unroll
      for (int g = 0; g < 4; ++g) {
        f32x4 rjv = *(const f32x4*)&Rsl[jblk * 32 + g * 8 + h * 4];
        float e0, e1, e2, e3;
        {
          float c0 = fminf(1.f, fmaxf(-1.f, sacc[4 * g + 0] * rsq * rjv[0]));
          float c1 = fminf(1.f, fmaxf(-1.f, sacc[4 * g + 1] * rsq * rjv[1]));
          float c2 = fminf(1.f, fmaxf(-1.f, sacc[4 * g + 2] * rsq * rjv[2]));
          float c3 = fminf(1.f, fmaxf(-1.f, sacc[4 * g + 3] * rsq * rjv[3]));
          e0 = __expf(c0); e1 = __expf(c1); e2 = __expf(c2); e3 = __expf(c3);
        }
        den += (e0 + e1) + (e2 + e3);
        pkA[g] = __builtin_bit_cast(u32, __builtin_amdgcn_cvt_pkrtz(e0, e1));
        pkB[g] = __builtin_bit_cast(u32, __builtin_amdgcn_cvt_pkrtz(e2, e3));
      }

      // P A-frags per k-chunk jc2 (j = (jblk*2+jc2)*16 + h*8 + 0..7):
      // send own group sel'd by OWN h, receive partner's, reassemble.
      #pragma unroll
      for (int jc2 = 0; jc2 < 2; ++jc2) {
        const u32 sA = h ? pkA[2 * jc2] : pkA[2 * jc2 + 1];
        const u32 sB = h ? pkB[2 * jc2] : pkB[2 * jc2 + 1];
        const u32 rA = (u32)__shfl_xor((int)sA, 32, 64);
        const u32 rB = (u32)__shfl_xor((int)sB, 32, 64);
        u32x4 uu;
        uu[0] = h ? rA : pkA[2 * jc2];         // e0,e1 (low lane's group)
        uu[1] = h ? rB : pkB[2 * jc2];         // e2,e3
        uu[2] = h ? pkA[2 * jc2 + 1] : rA;     // e4,e5 (high lane's group)
        uu[3] = h ? pkB[2 * jc2 + 1] : rB;     // e6,e7
        const f16x8 pa = __builtin_bit_cast(f16x8, uu);

        const int jcg = jblk * 2 + jc2;
        #pragma unroll
        for (int dblk = 0; dblk < 2; ++dblk) {
          const int voff = (dblk * 32 + lq) * 64 + (((jcg * 2 + h) ^ l7) << 3);
          f16x8 bv = *(const f16x8*)&Vsm[voff];
          oacc[dblk] = __builtin_amdgcn_mfma_f32_32x32x16_f16(pa, bv, oacc[dblk], 0, 0, 0);
        }
      }
    }
  }

  // epilogue: den (this lane covers its h/reg j-subset; partner the rest)
  const float dtot = den + __shfl_xor(den, 32, 64);
  const float inv = 1.f / dtot;            // valid for q = lq (both halves)

  #pragma unroll
  for (int g = 0; g < 4; ++g)
    #pragma unroll
    for (int i = 0; i < 4; ++i) {
      const int qr = i + 8 * g + 4 * h;    // C-row for reg r = 4g+i
      const float invq = __shfl(inv, i + 8 * g + 4 * h, 64);
      const size_t row = (size_t)bh * S + qrow0 + qr;
      out[row * HD + lq]      = oacc[0][4 * g + i] * invq;
      out[row * HD + 32 + lq] = oacc[1][4 * g + i] * invq;
    }
}

extern "C" void kernel_launch(void* const* d_in, const int* in_sizes, int n_in,
                              void* d_out, int out_size, void* d_ws, size_t ws_size,
                              hipStream_t stream) {
  const float* query = (const float*)d_in[0];
  const float* W     = (const float*)d_in[1];
  const float* bias  = (const float*)d_in[2];
  float* out = (float*)d_out;
  char* ws = (char*)d_ws;

  float*          qkv = (float*)ws;                          // dead after stats_k
  // fp16 split planes live only between split_k and gemm_mfma:
  unsigned short* A1 = (unsigned short*)(ws + 50331648);
  unsigned short* A2 = (unsigned short*)(ws + 58720256);
  unsigned short* W1 = (unsigned short*)(ws + 67108864);
  unsigned short* W2 = (unsigned short*)(ws + 73400320);
  // stats outputs reuse the (dead) split region:
  unsigned short* qhi = (unsigned short*)(ws + 50331648);
  unsigned short* qlo = (unsigned short*)(ws + 58720256);
  unsigned short* khi = (unsigned short*)(ws + 67108864);
  unsigned short* klo = (unsigned short*)(ws + 75497472);
  unsigned short* vt  = (unsigned short*)(ws + 83886080);
  float*          rsb = (float*)(ws + 92274688);

  split_k  <<<dim3(7168), 256, 0, stream>>>(query, W, A1, A2, W1, W2);
  gemm_mfma<<<dim3(24, 32), 256, 0, stream>>>(A1, A2, W1, W2, bias, qkv);
  stats_k  <<<dim3(32, 32), 256, 0, stream>>>(qkv, qhi, qlo, khi, klo, vt, rsb);
  attn_k   <<<dim3(512), 256, 0, stream>>>(qhi, qlo, khi, klo, vt, rsb, out);
}